// Round 10
// baseline (113.277 us; speedup 1.0000x reference)
//
#include <hip/hip_runtime.h>

typedef unsigned short u16;
typedef unsigned int u32;
typedef __attribute__((ext_vector_type(8))) short short8;
typedef __attribute__((ext_vector_type(4))) float f32x4;

#define TEXT 256
#define IMGW 32
#define SEQ 1280
#define NREAL 1279
#define NBH 32
#define DIM 512
#define N3 1536
#define NEG_INF -3.402823466e38f

__device__ __forceinline__ u16 f2bf(float f) {
    u32 u = __float_as_uint(f);
    return (u16)((u + 0x7FFFu + ((u >> 16) & 1u)) >> 16);
}
__device__ __forceinline__ u32 pack2(float x, float y) {
    return (u32)f2bf(x) | ((u32)f2bf(y) << 16);
}
// async global->LDS, 16B/lane; LDS dest wave-uniform base + lane*16
__device__ __forceinline__ void gl2lds16(const void* g, void* l) {
    __builtin_amdgcn_global_load_lds(
        (const __attribute__((address_space(1))) void*)g,
        (__attribute__((address_space(3))) void*)l, 16, 0, 0);
}
// swizzled LDS tile: rows of 64 u16 (128 B); logical chunk c (8 u16) of row r
// lives at physical slot (c+r)&7  ->  b128 frag reads are conflict-free.
__device__ __forceinline__ int swz64(int row, int ch) {
    return row * 64 + (((ch + row) & 7) << 3);   // u16 units
}

// ---------------------------------------------------------------------------
// prep: blocks [0,1280) cast x -> xb bf16 [5120][512] (pad row zero);
//       [1280,2048) transpose-cast w_qkv -> wqT; [2048,2304) w_out -> woT.
// ---------------------------------------------------------------------------
__global__ __launch_bounds__(256) void prep_k(
    const float* __restrict__ x, const float* __restrict__ w_qkv,
    const float* __restrict__ w_out, u16* __restrict__ xb,
    u16* __restrict__ wqT, u16* __restrict__ woT)
{
    __shared__ float tile[32][33];
    const int gid = blockIdx.x;
    const int t = threadIdx.x;
    if (gid < 1280) {
        const size_t idx = ((size_t)gid * 256 + t) * 8;
        const int m = (int)(idx >> 9);
        const int c = (int)(idx & 511);
        const int b = m / SEQ, tok = m - b * SEQ;
        uint4 o;
        if (tok < NREAL) {
            const float* s = x + ((size_t)b * NREAL + tok) * DIM + c;
            const float4 f1 = *(const float4*)s;
            const float4 f2 = *(const float4*)(s + 4);
            o.x = pack2(f1.x, f1.y); o.y = pack2(f1.z, f1.w);
            o.z = pack2(f2.x, f2.y); o.w = pack2(f2.z, f2.w);
        } else {
            o = make_uint4(0, 0, 0, 0);
        }
        *(uint4*)(xb + idx) = o;
    } else {
        const float* src; u16* dst; int K, N, bx, by;
        if (gid < 2048) {
            const int i = gid - 1280;
            src = w_qkv; dst = wqT; K = 512; N = 1536;
            bx = i % 48; by = i / 48;
        } else {
            const int i = gid - 2048;
            src = w_out; dst = woT; K = 512; N = 512;
            bx = i % 16; by = i / 16;
        }
        const int n0 = bx * 32, k0 = by * 32;
        const int r = t >> 3, c4 = (t & 7) * 4;
        const float4 f = *(const float4*)(src + (size_t)(k0 + r) * N + n0 + c4);
        tile[r][c4 + 0] = f.x; tile[r][c4 + 1] = f.y;
        tile[r][c4 + 2] = f.z; tile[r][c4 + 3] = f.w;
        __syncthreads();
        ushort4 o;
        o.x = f2bf(tile[c4 + 0][r]); o.y = f2bf(tile[c4 + 1][r]);
        o.z = f2bf(tile[c4 + 2][r]); o.w = f2bf(tile[c4 + 3][r]);
        *(ushort4*)(dst + (size_t)(n0 + r) * K + k0 + c4) = o;
    }
}

// ---------------------------------------------------------------------------
// MFMA qkv GEMM, BK=64, swizzled LDS, DOUBLE-BUFFERED staging (1 barrier/iter,
// loads overlap compute). Coalesced LDS-roundtrip epilogue (reuses staging
// LDS after a sync). Writes qb/kb [bh][1280][64] (q scaled 0.125) and
// vtb [bh][64][1280].
// ---------------------------------------------------------------------------
__global__ __launch_bounds__(256, 2) void qkv_mfma_k(
    const u16* __restrict__ xb, const u16* __restrict__ wqT,
    u16* __restrict__ qb, u16* __restrict__ kb, u16* __restrict__ vtb)
{
    __shared__ u16 smem[32768];   // 64 KB: buf b at b*16384 (As 8192 | Bs 8192)
    const int t = threadIdx.x;
    const int l = t & 63;
    const int w = __builtin_amdgcn_readfirstlane(t >> 6);
    const int wr = w >> 1, wc = w & 1;
    const int quad = l >> 4;
    const int m0 = blockIdx.y * 128, n0 = blockIdx.x * 128;

    const int dr = l >> 3;                  // row within an 8-row call
    const int cinv = ((l & 7) - dr) & 7;    // source k-chunk for this lane
    const u16* aS[4]; const u16* bS[4]; int co[4];
#pragma unroll
    for (int j = 0; j < 4; ++j) {
        const int r0 = j * 32 + w * 8;
        co[j] = r0 * 128;                   // byte offset within As/Bs region
        aS[j] = xb  + (size_t)(m0 + r0 + dr) * 512 + cinv * 8;
        bS[j] = wqT + (size_t)(n0 + r0 + dr) * 512 + cinv * 8;
    }

    auto STAGE = [&](int k0, int b) {
#pragma unroll
        for (int j = 0; j < 4; ++j) {
            gl2lds16(aS[j] + k0, (char*)smem + b * 32768 + co[j]);
            gl2lds16(bS[j] + k0, (char*)smem + b * 32768 + 16384 + co[j]);
        }
    };

    f32x4 acc[4][4];
    const f32x4 zf = {0.f, 0.f, 0.f, 0.f};
#pragma unroll
    for (int i = 0; i < 4; ++i)
#pragma unroll
        for (int j = 0; j < 4; ++j) acc[i][j] = zf;

    const int arow0 = wr * 64 + (l & 15);
    const int brow0 = wc * 64 + (l & 15);

    STAGE(0, 0);
    for (int k0 = 0; k0 < 512; k0 += 64) {
        const int cur = (k0 >> 6) & 1;
        __syncthreads();                       // drains cur buffer's loads
        if (k0 + 64 < 512) STAGE(k0 + 64, cur ^ 1);
        const u16* As = smem + cur * 16384;
        const u16* Bs = smem + cur * 16384 + 8192;
#pragma unroll
        for (int ks = 0; ks < 2; ++ks) {
            const int ch = quad + ks * 4;
            short8 af[4], bf[4];
#pragma unroll
            for (int i = 0; i < 4; ++i)
                af[i] = *(const short8*)(As + swz64(arow0 + i * 16, ch));
#pragma unroll
            for (int j = 0; j < 4; ++j)
                bf[j] = *(const short8*)(Bs + swz64(brow0 + j * 16, ch));
#pragma unroll
            for (int i = 0; i < 4; ++i)
#pragma unroll
                for (int j = 0; j < 4; ++j)
                    acc[i][j] = __builtin_amdgcn_mfma_f32_16x16x32_bf16(
                        af[i], bf[j], acc[i][j], 0, 0, 0);
        }
    }
    __syncthreads();                            // staging done before epi reuse

    const int which = n0 >> 9;              // 0=q 1=k 2=v
    const int hbase = (n0 & 511) >> 6;      // first of the 2 heads in tile
    const int b = m0 / SEQ, tok0 = m0 % SEQ;
    const int mq = quad * 4, nq = l & 15;

    if (which == 2) {
        // LDS as [feat 128][tok, stride 136]: b64 writes (4 consecutive toks)
#pragma unroll
        for (int i = 0; i < 4; ++i)
#pragma unroll
            for (int j = 0; j < 4; ++j) {
                const int feat = wc * 64 + j * 16 + nq;
                const int tloc = wr * 64 + i * 16 + mq;
                uint2 pw;
                pw.x = pack2(acc[i][j][0], acc[i][j][1]);
                pw.y = pack2(acc[i][j][2], acc[i][j][3]);
                *(uint2*)(smem + feat * 136 + tloc) = pw;
            }
        __syncthreads();
#pragma unroll
        for (int p = 0; p < 8; ++p) {
            const int fr = p * 16 + (t >> 4), ch2 = t & 15;
            const uint4 d4 = *(const uint4*)(smem + fr * 136 + ch2 * 8);
            const int h = hbase + (fr >> 6), d = fr & 63;
            *(uint4*)(vtb + ((size_t)(b * 8 + h) * 64 + d) * SEQ
                      + tok0 + ch2 * 8) = d4;
        }
    } else {
        const float qs = (which == 0) ? 0.125f : 1.0f;
        // LDS as [tok 128][feat, stride 136]: scalar writes, vector reads
#pragma unroll
        for (int i = 0; i < 4; ++i)
#pragma unroll
            for (int r = 0; r < 4; ++r) {
                const int tloc = wr * 64 + i * 16 + mq + r;
#pragma unroll
                for (int j = 0; j < 4; ++j) {
                    const int feat = wc * 64 + j * 16 + nq;
                    smem[tloc * 136 + feat] = f2bf(acc[i][j][r] * qs);
                }
            }
        __syncthreads();
        u16* const dst = (which == 0) ? qb : kb;
#pragma unroll
        for (int p = 0; p < 8; ++p) {
            const int tkl = p * 16 + (t >> 4), ch2 = t & 15;
            const uint4 d4 = *(const uint4*)(smem + tkl * 136 + ch2 * 8);
            const int h = hbase + (ch2 >> 3), d = (ch2 & 7) * 8;
            *(uint4*)(dst + ((size_t)(b * 8 + h) * SEQ + tok0 + tkl) * 64 + d)
                = d4;
        }
    }
}

// ---------------------------------------------------------------------------
// Fused MFMA flash attention, 64-query blocks, DOUBLE-BUFFERED K/V staging:
// one barrier per tile, loads for tile i+1 in flight during compute of i.
// blockIdx.x: 0..15 img (heavier, first), 16..19 text. Unified tile loop,
// arithmetic tile indexing (no local arrays -> no scratch), uniform-mode
// branches. S^T = K @ Q^T; p = exp(s) (logits bounded, shift-free);
// P^T via per-wave LDS; O^T = V^T @ P^T.
// ---------------------------------------------------------------------------
#define STAGEB(tb, Kd, Vd)                                                 \
    _Pragma("unroll")                                                      \
    for (int j_ = 0; j_ < 2; ++j_) {                                       \
        const int r0_ = (j_ * 4 + w) * 8;                                  \
        gl2lds16(kb + ((size_t)bh * SEQ + (tb) + r0_ + dr8) * 64           \
                 + cinv * 8, (char*)(Kd) + r0_ * 128);                     \
        gl2lds16(vtb + ((size_t)bh * 64 + r0_ + dr8) * SEQ + (tb)          \
                 + cinv * 8, (char*)(Vd) + r0_ * 128);                     \
    }

#define ATTN_TILE(mode, kbase, Kp, Vp)                                     \
    {                                                                      \
        f32x4 st[4];                                                       \
        _Pragma("unroll")                                                  \
        for (int gk = 0; gk < 4; ++gk) {                                   \
            const int R_ = 16 * gk + lane;                                 \
            f32x4 a_ = zf;                                                 \
            a_ = __builtin_amdgcn_mfma_f32_16x16x32_bf16(                  \
                *(const short8*)((Kp) + swz64(R_, quad)), qf0, a_,         \
                0, 0, 0);                                                  \
            a_ = __builtin_amdgcn_mfma_f32_16x16x32_bf16(                  \
                *(const short8*)((Kp) + swz64(R_, quad + 4)), qf1, a_,     \
                0, 0, 0);                                                  \
            st[gk] = a_;                                                   \
        }                                                                  \
        float sc[16];                                                      \
        _Pragma("unroll")                                                  \
        for (int gk = 0; gk < 4; ++gk)                                     \
        _Pragma("unroll")                                                  \
        for (int r = 0; r < 4; ++r) {                                      \
            float x_ = st[gk][r];                                          \
            const int kl_ = 16 * gk + 4 * quad + r;                        \
            if ((mode) == 1) {                                             \
                if ((kbase) + kl_ > qidx) x_ = NEG_INF;                    \
            } else if ((mode) == 2) {                                      \
                const int ki_ = (kbase) + kl_;                             \
                const int kr2_ = ki_ >> 5, kc2_ = ki_ & 31;                \
                if (kr2_ < rq - 4 || kr2_ > rq ||                          \
                    kc2_ < cq - 4 || kc2_ > cq) x_ = NEG_INF;              \
            }                                                              \
            sc[gk * 4 + r] = x_;                                           \
        }                                                                  \
        _Pragma("unroll")                                                  \
        for (int i2 = 0; i2 < 16; ++i2) {                                  \
            sc[i2] = __expf(sc[i2]); l_s += sc[i2];                        \
        }                                                                  \
        _Pragma("unroll")                                                  \
        for (int gk = 0; gk < 4; ++gk) {                                   \
            uint2 pw_;                                                     \
            pw_.x = pack2(sc[gk * 4 + 0], sc[gk * 4 + 1]);                 \
            pw_.y = pack2(sc[gk * 4 + 2], sc[gk * 4 + 3]);                 \
            *(uint2*)(plw + lane * 72 + 16 * gk + 4 * quad) = pw_;         \
        }                                                                  \
        const short8 bp0_ = *(const short8*)(plw + lane * 72 + quad * 8);  \
        const short8 bp1_ =                                                \
            *(const short8*)(plw + lane * 72 + 32 + quad * 8);             \
        _Pragma("unroll")                                                  \
        for (int gd = 0; gd < 4; ++gd) {                                   \
            const int R_ = 16 * gd + lane;                                 \
            acc_o[gd] = __builtin_amdgcn_mfma_f32_16x16x32_bf16(           \
                *(const short8*)((Vp) + swz64(R_, quad)), bp0_,            \
                acc_o[gd], 0, 0, 0);                                       \
            acc_o[gd] = __builtin_amdgcn_mfma_f32_16x16x32_bf16(           \
                *(const short8*)((Vp) + swz64(R_, quad + 4)), bp1_,        \
                acc_o[gd], 0, 0, 0);                                       \
        }                                                                  \
    }

__global__ __launch_bounds__(256, 2) void attn_k(
    const u16* __restrict__ qb, const u16* __restrict__ kb,
    const u16* __restrict__ vtb, u16* __restrict__ aob)
{
    __shared__ u16 KV[2][2][64 * 64];   // [buf][K/V], swizzled
    __shared__ u16 Pl[4][16 * 72];

    const int t = threadIdx.x;
    const int l = t & 63;
    const int w = __builtin_amdgcn_readfirstlane(t >> 6);
    const int lane = l & 15, quad = l >> 4;
    const int dr8 = l >> 3, cinv = ((l & 7) - dr8) & 7;
    const int bh = blockIdx.y;
    const int tl = blockIdx.x;                 // 0..15 img, 16..19 text
    const bool is_img = (tl < 16);
    const int tile = is_img ? tl : (tl - 16);
    const int qloc = w * 16 + lane;
    const int qidx = tile * 64 + qloc;         // text pos / image-linear pos
    const int qtok = (is_img ? TEXT : 0) + qidx;
    const int rq = qidx >> 5, cq = qidx & 31;

    const u16* qrow = qb + ((size_t)bh * SEQ + qtok) * 64 + quad * 8;
    const short8 qf0 = *(const short8*)(qrow);
    const short8 qf1 = *(const short8*)(qrow + 32);

    const f32x4 zf = {0.f, 0.f, 0.f, 0.f};
    f32x4 acc_o[4] = {zf, zf, zf, zf};
    float l_s = 0.f;
    u16* const plw = &Pl[w][0];

    // unified tile schedule: text block -> tiles 0..tile (causal on last);
    // img block -> 4 text tiles + nwt window tiles (box-masked)
    const int rbase = (tile >= 2) ? (2 * tile - 4) : 0;
    const int ib0 = rbase * IMGW;
    const int nwt = (2 * tile + 2 - rbase) >> 1;     // 1..3
    const int n = is_img ? (4 + nwt) : (tile + 1);

    auto TBASE = [&](int i) {
        return (is_img && i >= 4) ? (TEXT + ib0 + (i - 4) * 64) : (i * 64);
    };

    STAGEB(TBASE(0), KV[0][0], KV[0][1]);
    for (int i = 0; i < n; ++i) {
        __syncthreads();                        // drains buffer i&1's loads
        if (i + 1 < n) {
            const int tb2 = TBASE(i + 1);
            const int b2 = (i + 1) & 1;
            STAGEB(tb2, KV[b2][0], KV[b2][1]);
        }
        const int bc = i & 1;
        const int mode = is_img ? ((i >= 4) ? 2 : 0)
                                : ((i == tile) ? 1 : 0);
        const int kbase = is_img ? ((i >= 4) ? (ib0 + (i - 4) * 64) : 0)
                                 : (i * 64);
        ATTN_TILE(mode, kbase, KV[bc][0], KV[bc][1])
    }

    l_s += __shfl_xor(l_s, 16);
    l_s += __shfl_xor(l_s, 32);
    const float inv = 1.f / l_s;
    u16* orow = aob + ((size_t)bh * SEQ + qtok) * 64;
#pragma unroll
    for (int gd = 0; gd < 4; ++gd) {
        uint2 o_;
        o_.x = pack2(acc_o[gd][0] * inv, acc_o[gd][1] * inv);
        o_.y = pack2(acc_o[gd][2] * inv, acc_o[gd][3] * inv);
        *(uint2*)(orow + 16 * gd + 4 * quad) = o_;
    }
}

// ---------------------------------------------------------------------------
// MFMA out GEMM, BK=64 (one head per K-iter), swizzled LDS, double-buffered.
// ---------------------------------------------------------------------------
__global__ __launch_bounds__(256, 2) void out_mfma_k(
    const u16* __restrict__ aob, const u16* __restrict__ woT,
    const float* __restrict__ bias, float* __restrict__ out)
{
    __shared__ u16 smem[24576];   // 48 KB: buf b at b*12288 (As 8192 | Bs 4096)
    const int t = threadIdx.x;
    const int l = t & 63;
    const int w = __builtin_amdgcn_readfirstlane(t >> 6);
    const int wr = w >> 1, wc = w & 1;
    const int quad = l >> 4;
    const int m0 = blockIdx.y * 128, n0 = blockIdx.x * 64;
    const int b = m0 / SEQ, tok0 = m0 % SEQ;

    const int dr = l >> 3, cinv = ((l & 7) - dr) & 7;
    size_t aBase[4]; int coA[4];
#pragma unroll
    for (int j = 0; j < 4; ++j) {
        const int r0 = j * 32 + w * 8;
        coA[j] = r0 * 128;
        aBase[j] = (size_t)b * 8 * SEQ * 64
                 + (size_t)(tok0 + r0 + dr) * 64 + cinv * 8;
    }
    const u16* bS[2]; int coB[2];
#pragma unroll
    for (int j = 0; j < 2; ++j) {
        const int r0 = j * 32 + w * 8;
        coB[j] = r0 * 128;
        bS[j] = woT + (size_t)(n0 + r0 + dr) * 512 + cinv * 8;
    }

    auto STAGE = [&](int k0, int bf2) {
        const size_t hoff = (size_t)k0 * SEQ;   // one head per k-iter
#pragma unroll
        for (int j = 0; j < 4; ++j)
            gl2lds16(aob + aBase[j] + hoff,
                     (char*)smem + bf2 * 24576 + coA[j]);
#pragma unroll
        for (int j = 0; j < 2; ++j)
            gl2lds16(bS[j] + k0, (char*)smem + bf2 * 24576 + 16384 + coB[j]);
    };

    f32x4 acc[4][2];
    const f32x4 zf = {0.f, 0.f, 0.f, 0.f};
#pragma unroll
    for (int i = 0; i < 4; ++i) { acc[i][0] = zf; acc[i][1] = zf; }

    const int arow0 = wr * 64 + (l & 15);
    const int brow0 = wc * 32 + (l & 15);

    STAGE(0, 0);
    for (int k0 = 0; k0 < 512; k0 += 64) {
        const int cur = (k0 >> 6) & 1;
        __syncthreads();
        if (k0 + 64 < 512) STAGE(k0 + 64, cur ^ 1);
        const u16* As = smem + cur * 12288;
        const u16* Bs = smem + cur * 12288 + 8192;
#pragma unroll
        for (int ks = 0; ks < 2; ++ks) {
            const int ch = quad + ks * 4;
            short8 af[4], bf[2];
#pragma unroll
            for (int i = 0; i < 4; ++i)
                af[i] = *(const short8*)(As + swz64(arow0 + i * 16, ch));
#pragma unroll
            for (int j = 0; j < 2; ++j)
                bf[j] = *(const short8*)(Bs + swz64(brow0 + j * 16, ch));
#pragma unroll
            for (int i = 0; i < 4; ++i)
#pragma unroll
                for (int j = 0; j < 2; ++j)
                    acc[i][j] = __builtin_amdgcn_mfma_f32_16x16x32_bf16(
                        af[i], bf[j], acc[i][j], 0, 0, 0);
        }
    }

    const int mq = quad * 4, nq = l & 15;
#pragma unroll
    for (int i = 0; i < 4; ++i) {
#pragma unroll
        for (int r = 0; r < 4; ++r) {
            const int tok = tok0 + wr * 64 + i * 16 + mq + r;
            if (tok < NREAL) {
#pragma unroll
                for (int j = 0; j < 2; ++j) {
                    const int n = n0 + wc * 32 + j * 16 + nq;
                    out[((size_t)b * NREAL + tok) * DIM + n] =
                        acc[i][j][r] + bias[n];
                }
            }
        }
    }
}

extern "C" void kernel_launch(void* const* d_in, const int* in_sizes, int n_in,
                              void* d_out, int out_size, void* d_ws, size_t ws_size,
                              hipStream_t stream)
{
    const float* x     = (const float*)d_in[0];
    const float* w_qkv = (const float*)d_in[2];
    const float* w_out = (const float*)d_in[3];
    const float* b_out = (const float*)d_in[4];
    float* out = (float*)d_out;

    u16* xb  = (u16*)d_ws;                      // [5120][512]
    u16* aob = xb;                               // overlay (xb consumed first)
    u16* wqT = xb  + (size_t)5120 * 512;         // [1536][512]
    u16* woT = wqT + (size_t)1536 * 512;         // [512][512]
    u16* qb  = woT + (size_t)512 * 512;          // [32][1280][64]
    u16* kb  = qb  + (size_t)NBH * SEQ * 64;     // [32][1280][64]
    u16* vtb = kb  + (size_t)NBH * SEQ * 64;     // [32][64][1280]

    prep_k<<<2304, 256, 0, stream>>>(x, w_qkv, w_out, xb, wqT, woT);

    qkv_mfma_k<<<dim3(12, 40), 256, 0, stream>>>(xb, wqT, qb, kb, vtb);

    attn_k<<<dim3(20, NBH), 256, 0, stream>>>(qb, kb, vtb, aob);

    out_mfma_k<<<dim3(8, 40), 256, 0, stream>>>(aob, woT, b_out, out);
}

// Round 11
// 111.094 us; speedup vs baseline: 1.0196x; 1.0196x over previous
//
#include <hip/hip_runtime.h>

typedef unsigned short u16;
typedef unsigned int u32;
typedef __attribute__((ext_vector_type(8))) short short8;
typedef __attribute__((ext_vector_type(4))) float f32x4;

#define TEXT 256
#define IMGW 32
#define SEQ 1280
#define NREAL 1279
#define NBH 32
#define DIM 512
#define N3 1536
#define NEG_INF -3.402823466e38f

__device__ __forceinline__ u16 f2bf(float f) {
    u32 u = __float_as_uint(f);
    return (u16)((u + 0x7FFFu + ((u >> 16) & 1u)) >> 16);
}
__device__ __forceinline__ u32 pack2(float x, float y) {
    return (u32)f2bf(x) | ((u32)f2bf(y) << 16);
}
// async global->LDS, 16B/lane; LDS dest wave-uniform base + lane*16
__device__ __forceinline__ void gl2lds16(const void* g, void* l) {
    __builtin_amdgcn_global_load_lds(
        (const __attribute__((address_space(1))) void*)g,
        (__attribute__((address_space(3))) void*)l, 16, 0, 0);
}
// swizzled LDS tile: rows of 64 u16 (128 B); logical chunk c (8 u16) of row r
// lives at physical slot (c+r)&7  ->  b128 frag reads are conflict-free.
__device__ __forceinline__ int swz64(int row, int ch) {
    return row * 64 + (((ch + row) & 7) << 3);   // u16 units
}

// ---------------------------------------------------------------------------
// prep: blocks [0,1280) cast x -> xb bf16 [5120][512] (pad row zero);
//       [1280,2048) transpose-cast w_qkv -> wqT; [2048,2304) w_out -> woT.
// ---------------------------------------------------------------------------
__global__ __launch_bounds__(256) void prep_k(
    const float* __restrict__ x, const float* __restrict__ w_qkv,
    const float* __restrict__ w_out, u16* __restrict__ xb,
    u16* __restrict__ wqT, u16* __restrict__ woT)
{
    __shared__ float tile[32][33];
    const int gid = blockIdx.x;
    const int t = threadIdx.x;
    if (gid < 1280) {
        const size_t idx = ((size_t)gid * 256 + t) * 8;
        const int m = (int)(idx >> 9);
        const int c = (int)(idx & 511);
        const int b = m / SEQ, tok = m - b * SEQ;
        uint4 o;
        if (tok < NREAL) {
            const float* s = x + ((size_t)b * NREAL + tok) * DIM + c;
            const float4 f1 = *(const float4*)s;
            const float4 f2 = *(const float4*)(s + 4);
            o.x = pack2(f1.x, f1.y); o.y = pack2(f1.z, f1.w);
            o.z = pack2(f2.x, f2.y); o.w = pack2(f2.z, f2.w);
        } else {
            o = make_uint4(0, 0, 0, 0);
        }
        *(uint4*)(xb + idx) = o;
    } else {
        const float* src; u16* dst; int K, N, bx, by;
        if (gid < 2048) {
            const int i = gid - 1280;
            src = w_qkv; dst = wqT; K = 512; N = 1536;
            bx = i % 48; by = i / 48;
        } else {
            const int i = gid - 2048;
            src = w_out; dst = woT; K = 512; N = 512;
            bx = i % 16; by = i / 16;
        }
        const int n0 = bx * 32, k0 = by * 32;
        const int r = t >> 3, c4 = (t & 7) * 4;
        const float4 f = *(const float4*)(src + (size_t)(k0 + r) * N + n0 + c4);
        tile[r][c4 + 0] = f.x; tile[r][c4 + 1] = f.y;
        tile[r][c4 + 2] = f.z; tile[r][c4 + 3] = f.w;
        __syncthreads();
        ushort4 o;
        o.x = f2bf(tile[c4 + 0][r]); o.y = f2bf(tile[c4 + 1][r]);
        o.z = f2bf(tile[c4 + 2][r]); o.w = f2bf(tile[c4 + 3][r]);
        *(ushort4*)(dst + (size_t)(n0 + r) * K + k0 + c4) = o;
    }
}

// ---------------------------------------------------------------------------
// MFMA qkv GEMM, BK=64, swizzled LDS, coalesced LDS-roundtrip epilogue.
// Writes qb/kb [bh][1280][64] (q scaled 0.125) and vtb [bh][64][1280].
// ---------------------------------------------------------------------------
__global__ __launch_bounds__(256, 2) void qkv_mfma_k(
    const u16* __restrict__ xb, const u16* __restrict__ wqT,
    u16* __restrict__ qb, u16* __restrict__ kb, u16* __restrict__ vtb)
{
    __shared__ u16 smem[17408];            // 34 KB: staging 32 KB / epi 128x136
    u16* const As = smem;                   // [128][64] swizzled
    u16* const Bs = smem + 8192;
    const int t = threadIdx.x;
    const int l = t & 63;
    const int w = __builtin_amdgcn_readfirstlane(t >> 6);
    const int wr = w >> 1, wc = w & 1;
    const int quad = l >> 4;
    const int m0 = blockIdx.y * 128, n0 = blockIdx.x * 128;

    const int dr = l >> 3;                  // row within an 8-row call
    const int cinv = ((l & 7) - dr) & 7;    // source k-chunk for this lane
    const u16* aS[4]; const u16* bS[4]; int co[4];
#pragma unroll
    for (int j = 0; j < 4; ++j) {
        const int r0 = j * 32 + w * 8;
        co[j] = r0 * 128;                   // LDS byte offset (128 B rows)
        aS[j] = xb  + (size_t)(m0 + r0 + dr) * 512 + cinv * 8;
        bS[j] = wqT + (size_t)(n0 + r0 + dr) * 512 + cinv * 8;
    }

    f32x4 acc[4][4];
    const f32x4 zf = {0.f, 0.f, 0.f, 0.f};
#pragma unroll
    for (int i = 0; i < 4; ++i)
#pragma unroll
        for (int j = 0; j < 4; ++j) acc[i][j] = zf;

    const int arow0 = wr * 64 + (l & 15);
    const int brow0 = wc * 64 + (l & 15);

    for (int k0 = 0; k0 < 512; k0 += 64) {
#pragma unroll
        for (int j = 0; j < 4; ++j) {
            gl2lds16(aS[j] + k0, (char*)As + co[j]);
            gl2lds16(bS[j] + k0, (char*)Bs + co[j]);
        }
        __syncthreads();
#pragma unroll
        for (int ks = 0; ks < 2; ++ks) {
            const int ch = quad + ks * 4;
            short8 af[4], bf[4];
#pragma unroll
            for (int i = 0; i < 4; ++i)
                af[i] = *(const short8*)(As + swz64(arow0 + i * 16, ch));
#pragma unroll
            for (int j = 0; j < 4; ++j)
                bf[j] = *(const short8*)(Bs + swz64(brow0 + j * 16, ch));
#pragma unroll
            for (int i = 0; i < 4; ++i)
#pragma unroll
                for (int j = 0; j < 4; ++j)
                    acc[i][j] = __builtin_amdgcn_mfma_f32_16x16x32_bf16(
                        af[i], bf[j], acc[i][j], 0, 0, 0);
        }
        __syncthreads();
    }

    const int which = n0 >> 9;              // 0=q 1=k 2=v
    const int hbase = (n0 & 511) >> 6;      // first of the 2 heads in tile
    const int b = m0 / SEQ, tok0 = m0 % SEQ;
    const int mq = quad * 4, nq = l & 15;

    if (which == 2) {
        // LDS as [feat 128][tok, stride 136]: b64 writes (4 consecutive toks)
#pragma unroll
        for (int i = 0; i < 4; ++i)
#pragma unroll
            for (int j = 0; j < 4; ++j) {
                const int feat = wc * 64 + j * 16 + nq;
                const int tloc = wr * 64 + i * 16 + mq;
                uint2 pw;
                pw.x = pack2(acc[i][j][0], acc[i][j][1]);
                pw.y = pack2(acc[i][j][2], acc[i][j][3]);
                *(uint2*)(smem + feat * 136 + tloc) = pw;
            }
        __syncthreads();
#pragma unroll
        for (int p = 0; p < 8; ++p) {
            const int fr = p * 16 + (t >> 4), ch2 = t & 15;
            const uint4 d4 = *(const uint4*)(smem + fr * 136 + ch2 * 8);
            const int h = hbase + (fr >> 6), d = fr & 63;
            *(uint4*)(vtb + ((size_t)(b * 8 + h) * 64 + d) * SEQ
                      + tok0 + ch2 * 8) = d4;
        }
    } else {
        const float qs = (which == 0) ? 0.125f : 1.0f;
        // LDS as [tok 128][feat, stride 136]: scalar writes, vector reads
#pragma unroll
        for (int i = 0; i < 4; ++i)
#pragma unroll
            for (int r = 0; r < 4; ++r) {
                const int tloc = wr * 64 + i * 16 + mq + r;
#pragma unroll
                for (int j = 0; j < 4; ++j) {
                    const int feat = wc * 64 + j * 16 + nq;
                    smem[tloc * 136 + feat] = f2bf(acc[i][j][r] * qs);
                }
            }
        __syncthreads();
        u16* const dst = (which == 0) ? qb : kb;
#pragma unroll
        for (int p = 0; p < 8; ++p) {
            const int tkl = p * 16 + (t >> 4), ch2 = t & 15;
            const uint4 d4 = *(const uint4*)(smem + tkl * 136 + ch2 * 8);
            const int h = hbase + (ch2 >> 3), d = (ch2 & 7) * 8;
            *(uint4*)(dst + ((size_t)(b * 8 + h) * SEQ + tok0 + tkl) * 64 + d)
                = d4;
        }
    }
}

// ---------------------------------------------------------------------------
// Fused MFMA flash attention. blockIdx.x: 0..15 img tiles (heavier, first),
// 16..19 text tiles. S^T = K @ Q^T; p = exp(s) (logits bounded, shift-free);
// P^T via per-wave LDS; O^T = V^T @ P^T. K/V staged by global_load_lds into
// swizzled 64x64 tiles.
// ---------------------------------------------------------------------------
#define STAGE(tb)                                                          \
    _Pragma("unroll")                                                      \
    for (int j_ = 0; j_ < 2; ++j_) {                                       \
        const int r0_ = (j_ * 4 + w) * 8;                                  \
        gl2lds16(kb + ((size_t)bh * SEQ + (tb) + r0_ + dr8) * 64           \
                 + cinv * 8, (char*)Ks + r0_ * 128);                       \
        gl2lds16(vtb + ((size_t)bh * 64 + r0_ + dr8) * SEQ + (tb)          \
                 + cinv * 8, (char*)Vt + r0_ * 128);                       \
    }

#define ATTN_TILE(MODE, kbase)                                             \
    {                                                                      \
        f32x4 st[4];                                                       \
        _Pragma("unroll")                                                  \
        for (int gk = 0; gk < 4; ++gk) {                                   \
            const int R_ = 16 * gk + lane;                                 \
            f32x4 a_ = zf;                                                 \
            a_ = __builtin_amdgcn_mfma_f32_16x16x32_bf16(                  \
                *(const short8*)(Ks + swz64(R_, quad)), qf0, a_, 0, 0, 0); \
            a_ = __builtin_amdgcn_mfma_f32_16x16x32_bf16(                  \
                *(const short8*)(Ks + swz64(R_, quad + 4)), qf1, a_,       \
                0, 0, 0);                                                  \
            st[gk] = a_;                                                   \
        }                                                                  \
        float sc[16];                                                      \
        _Pragma("unroll")                                                  \
        for (int gk = 0; gk < 4; ++gk)                                     \
        _Pragma("unroll")                                                  \
        for (int r = 0; r < 4; ++r) {                                      \
            float x_ = st[gk][r];                                          \
            const int kl_ = 16 * gk + 4 * quad + r;                        \
            if ((MODE) == 1) {                                             \
                if ((kbase) + kl_ > qidx) x_ = NEG_INF;                    \
            }                                                              \
            if ((MODE) == 2) {                                             \
                const int ki_ = (kbase) + kl_;                             \
                const int kr2_ = ki_ >> 5, kc2_ = ki_ & 31;                \
                if (kr2_ < rq - 4 || kr2_ > rq ||                          \
                    kc2_ < cq - 4 || kc2_ > cq) x_ = NEG_INF;              \
            }                                                              \
            sc[gk * 4 + r] = x_;                                           \
        }                                                                  \
        _Pragma("unroll")                                                  \
        for (int i = 0; i < 16; ++i) {                                     \
            sc[i] = __expf(sc[i]); l_s += sc[i];                           \
        }                                                                  \
        _Pragma("unroll")                                                  \
        for (int gk = 0; gk < 4; ++gk) {                                   \
            uint2 pw_;                                                     \
            pw_.x = pack2(sc[gk * 4 + 0], sc[gk * 4 + 1]);                 \
            pw_.y = pack2(sc[gk * 4 + 2], sc[gk * 4 + 3]);                 \
            *(uint2*)(plw + lane * 72 + 16 * gk + 4 * quad) = pw_;         \
        }                                                                  \
        const short8 bp0_ = *(const short8*)(plw + lane * 72 + quad * 8);  \
        const short8 bp1_ =                                                \
            *(const short8*)(plw + lane * 72 + 32 + quad * 8);             \
        _Pragma("unroll")                                                  \
        for (int gd = 0; gd < 4; ++gd) {                                   \
            const int R_ = 16 * gd + lane;                                 \
            acc_o[gd] = __builtin_amdgcn_mfma_f32_16x16x32_bf16(           \
                *(const short8*)(Vt + swz64(R_, quad)), bp0_, acc_o[gd],   \
                0, 0, 0);                                                  \
            acc_o[gd] = __builtin_amdgcn_mfma_f32_16x16x32_bf16(           \
                *(const short8*)(Vt + swz64(R_, quad + 4)), bp1_,          \
                acc_o[gd], 0, 0, 0);                                       \
        }                                                                  \
    }

__global__ __launch_bounds__(256, 2) void attn_k(
    const u16* __restrict__ qb, const u16* __restrict__ kb,
    const u16* __restrict__ vtb, u16* __restrict__ aob)
{
    __shared__ u16 Ks[64 * 64];      // swizzled
    __shared__ u16 Vt[64 * 64];      // swizzled
    __shared__ u16 Pl[4][16 * 72];

    const int t = threadIdx.x;
    const int l = t & 63;
    const int w = __builtin_amdgcn_readfirstlane(t >> 6);
    const int lane = l & 15, quad = l >> 4;
    const int dr8 = l >> 3, cinv = ((l & 7) - dr8) & 7;
    const int bh = blockIdx.y;
    const int tl = blockIdx.x;                 // 0..15 img, 16..19 text
    const bool is_img = (tl < 16);
    const int tile = is_img ? tl : (tl - 16);
    const int qloc = w * 16 + lane;
    const int qidx = tile * 64 + qloc;         // text pos / image-linear pos
    const int qtok = (is_img ? TEXT : 0) + qidx;
    const int rq = qidx >> 5, cq = qidx & 31;

    const u16* qrow = qb + ((size_t)bh * SEQ + qtok) * 64 + quad * 8;
    const short8 qf0 = *(const short8*)(qrow);
    const short8 qf1 = *(const short8*)(qrow + 32);

    const f32x4 zf = {0.f, 0.f, 0.f, 0.f};
    f32x4 acc_o[4] = {zf, zf, zf, zf};
    float l_s = 0.f;
    u16* const plw = &Pl[w][0];

    if (!is_img) {
        for (int kt = 0; kt <= tile; ++kt) {
            __syncthreads();
            STAGE(kt * 64);
            __syncthreads();
            if (kt == tile) { ATTN_TILE(1, kt * 64) }
            else            { ATTN_TILE(0, 0) }
        }
    } else {
        for (int kt = 0; kt < 4; ++kt) {
            __syncthreads();
            STAGE(kt * 64);
            __syncthreads();
            ATTN_TILE(0, 0)
        }
        const int rbase = (tile >= 2) ? (2 * tile - 4) : 0;
        const int ntok = (2 * tile + 2 - rbase) * IMGW;   // 64,128,192
        const int ib0 = rbase * IMGW;
        for (int c0 = 0; c0 < ntok; c0 += 64) {
            __syncthreads();
            STAGE(TEXT + ib0 + c0);
            __syncthreads();
            ATTN_TILE(2, ib0 + c0)
        }
    }

    l_s += __shfl_xor(l_s, 16);
    l_s += __shfl_xor(l_s, 32);
    const float inv = 1.f / l_s;
    u16* orow = aob + ((size_t)bh * SEQ + qtok) * 64;
#pragma unroll
    for (int gd = 0; gd < 4; ++gd) {
        uint2 o_;
        o_.x = pack2(acc_o[gd][0] * inv, acc_o[gd][1] * inv);
        o_.y = pack2(acc_o[gd][2] * inv, acc_o[gd][3] * inv);
        *(uint2*)(orow + 16 * gd + 4 * quad) = o_;
    }
}

// ---------------------------------------------------------------------------
// MFMA out GEMM, BK=64 (one head per K-iter), swizzled LDS.
// ---------------------------------------------------------------------------
__global__ __launch_bounds__(256, 2) void out_mfma_k(
    const u16* __restrict__ aob, const u16* __restrict__ woT,
    const float* __restrict__ bias, float* __restrict__ out)
{
    __shared__ u16 As[128 * 64];    // 16 KB swizzled
    __shared__ u16 Bs[64 * 64];     // 8 KB swizzled
    const int t = threadIdx.x;
    const int l = t & 63;
    const int w = __builtin_amdgcn_readfirstlane(t >> 6);
    const int wr = w >> 1, wc = w & 1;
    const int quad = l >> 4;
    const int m0 = blockIdx.y * 128, n0 = blockIdx.x * 64;
    const int b = m0 / SEQ, tok0 = m0 % SEQ;

    const int dr = l >> 3, cinv = ((l & 7) - dr) & 7;
    size_t aBase[4]; int coA[4];
#pragma unroll
    for (int j = 0; j < 4; ++j) {
        const int r0 = j * 32 + w * 8;
        coA[j] = r0 * 128;
        aBase[j] = (size_t)b * 8 * SEQ * 64
                 + (size_t)(tok0 + r0 + dr) * 64 + cinv * 8;
    }
    const u16* bS[2]; int coB[2];
#pragma unroll
    for (int j = 0; j < 2; ++j) {
        const int r0 = j * 32 + w * 8;
        coB[j] = r0 * 128;
        bS[j] = woT + (size_t)(n0 + r0 + dr) * 512 + cinv * 8;
    }

    f32x4 acc[4][2];
    const f32x4 zf = {0.f, 0.f, 0.f, 0.f};
#pragma unroll
    for (int i = 0; i < 4; ++i) { acc[i][0] = zf; acc[i][1] = zf; }

    const int arow0 = wr * 64 + (l & 15);
    const int brow0 = wc * 32 + (l & 15);

    for (int k0 = 0; k0 < 512; k0 += 64) {
        const size_t hoff = (size_t)k0 * SEQ;   // h advances one head per iter
#pragma unroll
        for (int j = 0; j < 4; ++j)
            gl2lds16(aob + aBase[j] + hoff, (char*)As + coA[j]);
#pragma unroll
        for (int j = 0; j < 2; ++j)
            gl2lds16(bS[j] + k0, (char*)Bs + coB[j]);
        __syncthreads();
#pragma unroll
        for (int ks = 0; ks < 2; ++ks) {
            const int ch = quad + ks * 4;
            short8 af[4], bf[2];
#pragma unroll
            for (int i = 0; i < 4; ++i)
                af[i] = *(const short8*)(As + swz64(arow0 + i * 16, ch));
#pragma unroll
            for (int j = 0; j < 2; ++j)
                bf[j] = *(const short8*)(Bs + swz64(brow0 + j * 16, ch));
#pragma unroll
            for (int i = 0; i < 4; ++i)
#pragma unroll
                for (int j = 0; j < 2; ++j)
                    acc[i][j] = __builtin_amdgcn_mfma_f32_16x16x32_bf16(
                        af[i], bf[j], acc[i][j], 0, 0, 0);
        }
        __syncthreads();
    }

    const int mq = quad * 4, nq = l & 15;
#pragma unroll
    for (int i = 0; i < 4; ++i) {
#pragma unroll
        for (int r = 0; r < 4; ++r) {
            const int tok = tok0 + wr * 64 + i * 16 + mq + r;
            if (tok < NREAL) {
#pragma unroll
                for (int j = 0; j < 2; ++j) {
                    const int n = n0 + wc * 32 + j * 16 + nq;
                    out[((size_t)b * NREAL + tok) * DIM + n] =
                        acc[i][j][r] + bias[n];
                }
            }
        }
    }
}

extern "C" void kernel_launch(void* const* d_in, const int* in_sizes, int n_in,
                              void* d_out, int out_size, void* d_ws, size_t ws_size,
                              hipStream_t stream)
{
    const float* x     = (const float*)d_in[0];
    const float* w_qkv = (const float*)d_in[2];
    const float* w_out = (const float*)d_in[3];
    const float* b_out = (const float*)d_in[4];
    float* out = (float*)d_out;

    u16* xb  = (u16*)d_ws;                      // [5120][512]
    u16* aob = xb;                               // overlay (xb consumed first)
    u16* wqT = xb  + (size_t)5120 * 512;         // [1536][512]
    u16* woT = wqT + (size_t)1536 * 512;         // [512][512]
    u16* qb  = woT + (size_t)512 * 512;          // [32][1280][64]
    u16* kb  = qb  + (size_t)NBH * SEQ * 64;     // [32][1280][64]
    u16* vtb = kb  + (size_t)NBH * SEQ * 64;     // [32][64][1280]

    prep_k<<<2304, 256, 0, stream>>>(x, w_qkv, w_out, xb, wqT, woT);

    qkv_mfma_k<<<dim3(12, 40), 256, 0, stream>>>(xb, wqT, qb, kb, vtb);

    attn_k<<<dim3(20, NBH), 256, 0, stream>>>(qb, kb, vtb, aob);

    out_mfma_k<<<dim3(8, 40), 256, 0, stream>>>(aob, woT, b_out, out);
}